// Round 2
// baseline (244.946 us; speedup 1.0000x reference)
//
#include <hip/hip_runtime.h>

// KronLinear fused kernel for MI355X (gfx950).
// out[n, a2*64+b2] = bias[a2*64+b2]
//   + sum_{r,a1,b1} x[n, a1*64+b1] * B[b2&3, b1, r*16+(b2>>2)] * A[r, a1, a2]
// Two fused per-tile GEMMs via bf16 MFMA 16x16x32, T kept in LDS.

typedef __attribute__((ext_vector_type(8))) short bf16x8;
typedef __attribute__((ext_vector_type(4))) float f32x4;

__device__ __forceinline__ unsigned short f2bf(float f) {
    unsigned int u = __builtin_bit_cast(unsigned int, f);
    unsigned int r = u + 0x7fffu + ((u >> 16) & 1u);   // round-to-nearest-even
    return (unsigned short)(r >> 16);
}

// ---------------------------------------------------------------------------
// Prep: pack Bq (stage-1 B-operand) and A'' (stage-2 B-operand) into
// MFMA-fragment-ordered bf16 tables in workspace.
//   ws[0      .. 16384) : Bq_frag[ct=16][ks=2][lane=64][e=8]
//   ws[16384  .. 32768) : A_frag [at=4 ][ks=8][lane=64][e=8]
// Fragment value convention (16x16x32, B-operand): B[k = ks*32+(l>>4)*8+e][col = ct*16+(l&15)]
// ---------------------------------------------------------------------------
__global__ __launch_bounds__(256) void kron_prep(const float* __restrict__ A,
                                                 const float* __restrict__ B,
                                                 unsigned short* __restrict__ ws)
{
    int f = blockIdx.x * 256 + threadIdx.x;   // 0 .. 32768
    if (f < 16384) {
        int e = f & 7, l = (f >> 3) & 63, ks = (f >> 9) & 1, ct = f >> 10;
        int b1 = ks * 32 + (l >> 4) * 8 + e;          // k index (stage-1 K = b1)
        int c  = ct * 16 + (l & 15);                  // column c = r*64 + b2
        int bb = c & 63, rr = c >> 6;
        float v = B[(bb & 3) * 4096 + b1 * 64 + (rr * 16 + (bb >> 2))];
        ws[f] = f2bf(v);
    } else {
        int f2 = f - 16384;
        int e = f2 & 7, l = (f2 >> 3) & 63, ks = (f2 >> 9) & 7, at = f2 >> 12;
        int k = ks * 32 + (l >> 4) * 8 + e;           // k = r*64 + a1 (stage-2 K)
        int rr = k >> 6, a1 = k & 63;
        int a2 = at * 16 + (l & 15);
        float v = A[rr * 4096 + a1 * 64 + a2];
        ws[16384 + f2] = f2bf(v);
    }
}

// ---------------------------------------------------------------------------
// Main fused kernel: one 64x64 input tile (one n) per 256-thread block.
// LDS: Xs = bf16 X tile [a1=64][b1=64]   (XOR-swizzled rows, 8 KB)
//      Ts = bf16 T     [c=256][a1=64]    (XOR-swizzled rows, 32 KB)
// Swizzle: byte_off_in_row ^= (row&7)<<4  (keeps 16B groups intact)
// ---------------------------------------------------------------------------
__global__ __launch_bounds__(256, 2) void kron_main(const float* __restrict__ x,
                                                    const float* __restrict__ bias,
                                                    const unsigned short* __restrict__ ws,
                                                    float* __restrict__ out)
{
    __shared__ unsigned short Xs[64 * 64];    // 8 KB
    __shared__ unsigned short Ts[256 * 64];   // 32 KB

    const int n = blockIdx.x;
    const float* __restrict__ xp = x + (size_t)n * 4096;
    float* __restrict__ op = out + (size_t)n * 4096;

    const int t  = threadIdx.x;
    const int w  = t >> 6;       // wave 0..3
    const int l  = t & 63;       // lane
    const int lr = l & 15;       // row/col within 16
    const int lg = l >> 4;       // k-group 0..3

    // ---- X load (4096 f32, coalesced float4) -> bf16 swizzled LDS ----
    #pragma unroll
    for (int it = 0; it < 4; ++it) {
        int idx = it * 1024 + t * 4;                       // float index in tile
        float4 v = *reinterpret_cast<const float4*>(xp + idx);
        int a1 = idx >> 6, b1 = idx & 63;
        unsigned int p0 = (unsigned int)f2bf(v.x) | ((unsigned int)f2bf(v.y) << 16);
        unsigned int p1 = (unsigned int)f2bf(v.z) | ((unsigned int)f2bf(v.w) << 16);
        int colb = (b1 * 2) ^ ((a1 & 7) << 4);
        *reinterpret_cast<uint2*>(reinterpret_cast<char*>(Xs) + a1 * 128 + colb) =
            make_uint2(p0, p1);
    }
    __syncthreads();

    // ---- stage 1: T(64x256) = X(64x64) @ Bq(64x256); wave w owns ct = 4w..4w+3
    f32x4 acc[4][4];   // [a1t][ci]
    #pragma unroll
    for (int i = 0; i < 4; ++i)
        #pragma unroll
        for (int j = 0; j < 4; ++j)
            acc[i][j] = (f32x4){0.f, 0.f, 0.f, 0.f};

    const unsigned short* __restrict__ Bq = ws;          // [ct][ks][lane][8]
    #pragma unroll
    for (int ks = 0; ks < 2; ++ks) {
        bf16x8 bfrag[4];
        #pragma unroll
        for (int ci = 0; ci < 4; ++ci) {
            int ct = w * 4 + ci;
            bfrag[ci] = *reinterpret_cast<const bf16x8*>(Bq + ((ct * 2 + ks) * 64 + l) * 8);
        }
        #pragma unroll
        for (int a1t = 0; a1t < 4; ++a1t) {
            int row  = a1t * 16 + lr;
            int colb = ((ks * 32 + lg * 8) * 2) ^ ((row & 7) << 4);
            bf16x8 afrag = *reinterpret_cast<const bf16x8*>(
                reinterpret_cast<const char*>(Xs) + row * 128 + colb);
            #pragma unroll
            for (int ci = 0; ci < 4; ++ci)
                acc[a1t][ci] = __builtin_amdgcn_mfma_f32_16x16x32_bf16(
                    afrag, bfrag[ci], acc[a1t][ci], 0, 0, 0);
        }
    }

    // D layout: row=(l>>4)*4+e, col=l&15  ->  T[a1t*16+lg*4+e][ct*16+lr]
    // store into Ts[c][a1] (bf16, swizzled)
    #pragma unroll
    for (int a1t = 0; a1t < 4; ++a1t) {
        #pragma unroll
        for (int ci = 0; ci < 4; ++ci) {
            int ct   = w * 4 + ci;
            int crow = ct * 16 + lr;          // c
            int a1c  = a1t * 16 + lg * 4;     // a1 base (4 consecutive)
            f32x4 d = acc[a1t][ci];
            unsigned int p0 = (unsigned int)f2bf(d[0]) | ((unsigned int)f2bf(d[1]) << 16);
            unsigned int p1 = (unsigned int)f2bf(d[2]) | ((unsigned int)f2bf(d[3]) << 16);
            int colb = (a1c * 2) ^ ((crow & 7) << 4);
            *reinterpret_cast<uint2*>(reinterpret_cast<char*>(Ts) + crow * 128 + colb) =
                make_uint2(p0, p1);
        }
    }
    __syncthreads();

    // ---- stage 2: out^T tile [b2, a2] = T''^T (b2 x k) @ A''(k x a2), K=256
    // wave w owns a2-tile at = w, all 4 b2-tiles
    f32x4 acc2[4];
    #pragma unroll
    for (int j = 0; j < 4; ++j) acc2[j] = (f32x4){0.f, 0.f, 0.f, 0.f};

    const unsigned short* __restrict__ Af = ws + 16384;  // [at][ks][lane][8]
    #pragma unroll
    for (int ks = 0; ks < 8; ++ks) {
        bf16x8 bop = *reinterpret_cast<const bf16x8*>(Af + ((w * 8 + ks) * 64 + l) * 8);
        #pragma unroll
        for (int bt = 0; bt < 4; ++bt) {
            // A-op: row = b2 = bt*16+lr, k = ks*32+lg*8+e
            // T''[k,b2] = Ts[c = (ks>>1)*64 + bt*16 + lr][a1 = (ks&1)*32 + lg*8 + e]
            int crow = (ks >> 1) * 64 + bt * 16 + lr;
            int a1c  = (ks & 1) * 32 + lg * 8;
            int colb = (a1c * 2) ^ ((crow & 7) << 4);
            bf16x8 aop = *reinterpret_cast<const bf16x8*>(
                reinterpret_cast<const char*>(Ts) + crow * 128 + colb);
            acc2[bt] = __builtin_amdgcn_mfma_f32_16x16x32_bf16(aop, bop, acc2[bt], 0, 0, 0);
        }
    }

    // ---- epilogue: D row = b2 = bt*16+lg*4+e, col = a2 = w*16+lr
    #pragma unroll
    for (int bt = 0; bt < 4; ++bt) {
        int a2  = w * 16 + lr;
        int b2  = bt * 16 + lg * 4;
        int idx = a2 * 64 + b2;
        float4 bv = *reinterpret_cast<const float4*>(bias + idx);
        f32x4 d = acc2[bt];
        float4 o = make_float4(d[0] + bv.x, d[1] + bv.y, d[2] + bv.z, d[3] + bv.w);
        *reinterpret_cast<float4*>(op + idx) = o;
    }
}

extern "C" void kernel_launch(void* const* d_in, const int* in_sizes, int n_in,
                              void* d_out, int out_size, void* d_ws, size_t ws_size,
                              hipStream_t stream) {
    const float* x    = (const float*)d_in[0];
    const float* A    = (const float*)d_in[1];
    const float* B    = (const float*)d_in[2];
    const float* bias = (const float*)d_in[3];
    float* out = (float*)d_out;
    unsigned short* ws = (unsigned short*)d_ws;

    // pack fragment tables (ws re-poisoned before every launch -> rebuild)
    kron_prep<<<128, 256, 0, stream>>>(A, B, ws);
    // 8192 input tiles of 64x64
    kron_main<<<8192, 256, 0, stream>>>(x, bias, ws, out);
}